// Round 1
// baseline (863.372 us; speedup 1.0000x reference)
//
#include <hip/hip_runtime.h>

#define TN 25
#define BN 4096
#define LN 512
#define NEG_INF (-__builtin_huge_valf())

// ---- 32-lane (half-wave) butterfly reductions via ds_swizzle (imm = xor<<10 | 0x1f) ----
__device__ __forceinline__ float gmax32(float x) {
  x = fmaxf(x, __int_as_float(__builtin_amdgcn_ds_swizzle(__float_as_int(x), 0x041F)));
  x = fmaxf(x, __int_as_float(__builtin_amdgcn_ds_swizzle(__float_as_int(x), 0x081F)));
  x = fmaxf(x, __int_as_float(__builtin_amdgcn_ds_swizzle(__float_as_int(x), 0x101F)));
  x = fmaxf(x, __int_as_float(__builtin_amdgcn_ds_swizzle(__float_as_int(x), 0x201F)));
  x = fmaxf(x, __int_as_float(__builtin_amdgcn_ds_swizzle(__float_as_int(x), 0x401F)));
  return x;
}
__device__ __forceinline__ float gsum32(float x) {
  x = x + __int_as_float(__builtin_amdgcn_ds_swizzle(__float_as_int(x), 0x041F));
  x = x + __int_as_float(__builtin_amdgcn_ds_swizzle(__float_as_int(x), 0x081F));
  x = x + __int_as_float(__builtin_amdgcn_ds_swizzle(__float_as_int(x), 0x101F));
  x = x + __int_as_float(__builtin_amdgcn_ds_swizzle(__float_as_int(x), 0x201F));
  x = x + __int_as_float(__builtin_amdgcn_ds_swizzle(__float_as_int(x), 0x401F));
  return x;
}

// ---- fully unrolled inner loop over prev (template gives ICE for ds_swizzle imm) ----
// Viterbi: v = (score[prev] + trans[prev][j]) + em   -- EXACT order match vs reference
// Forward: s += exp(alpha[prev]-m) * exp(trans[prev][j])
template <int P>
__device__ __forceinline__ void inner_step(int score_i, int ea_i,
                                           const float (&tc)[TN], const float (&ec)[TN],
                                           float em, float& best, int& barg,
                                           float& s0, float& s1) {
  float sp = __int_as_float(__builtin_amdgcn_ds_swizzle(score_i, (P << 5)));  // bcast lane P in 32-group
  float v = (sp + tc[P]) + em;
  if (v > best) { best = v; barg = P; }   // ascending prev + strict '>' == jnp first-max
  float ep = __int_as_float(__builtin_amdgcn_ds_swizzle(ea_i, (P << 5)));
  if constexpr ((P & 1) == 0) { s0 = fmaf(ep, ec[P], s0); } else { s1 = fmaf(ep, ec[P], s1); }
  if constexpr (P + 1 < TN) inner_step<P + 1>(score_i, ea_i, tc, ec, em, best, barg, s0, s1);
}

// ============================ kernel 1: fused forward (NLL) + Viterbi ============================
__global__ __launch_bounds__(256) void crf_main(
    const float* __restrict__ emis, const int* __restrict__ tags,
    const float* __restrict__ trans, const float* __restrict__ startT,
    const float* __restrict__ endT, float* __restrict__ nll_out,
    unsigned char* __restrict__ hist, unsigned char* __restrict__ mmap,
    int* __restrict__ lastTagOut) {
  __shared__ float ltr[TN * TN];
  const int tid = threadIdx.x;
  for (int i = tid; i < TN * TN; i += 256) ltr[i] = trans[i];
  __syncthreads();

  const int j = tid & 31;                       // state owned by this lane (valid if < 25)
  const int b = (blockIdx.x * 256 + tid) >> 5;  // batch element
  const bool act = (j < TN);
  const int jj = act ? j : 0;                   // clamped for safe LDS addressing

  // per-lane transition column (trans[prev][j]) and its exp, in registers
  float tc[TN], ec[TN];
#pragma unroll
  for (int p = 0; p < TN; ++p) {
    float tv = ltr[p * TN + jj];
    tc[p] = tv;
    ec[p] = __expf(tv);
  }

  const float startv = act ? startT[j] : NEG_INF;
  const float endv   = act ? endT[j]   : NEG_INF;

  // t = 0
  const float* emp = emis + (size_t)b * TN;
  float em0 = act ? emp[j] : 0.0f;
  int tag = tags[b];
  float alpha = startv + em0;   // -inf on inactive lanes
  float score = alpha;          // exact: fl(start + em), matches reference init
  float num_acc = (j == tag) ? alpha : 0.0f;
  int ptag = tag;
  int M = j;                                     // chunk-composed backpointer map
  const int bp_base = (tid & 32) << 2;           // byte base of this 32-group for ds_bpermute

#pragma unroll 1
  for (int t = 1; t < LN; ++t) {
    emp += (size_t)BN * TN;
    float em = act ? emp[j] : 0.0f;
    int tg = tags[(size_t)t * BN + b];

    // forward prep: single max over alpha (slack in NLL tolerance allows factored LSE)
    float mA = gmax32(alpha);
    float ea = __expf(alpha - mA);               // 0 on inactive lanes (alpha = -inf)

    int score_i = __float_as_int(score);
    int ea_i = __float_as_int(ea);
    float best = NEG_INF; int barg = 0; float s0 = 0.0f, s1 = 0.0f;
    inner_step<0>(score_i, ea_i, tc, ec, em, best, barg, s0, s1);

    score = best;                                // includes em, bitwise == reference
    float alpha_new = __logf(s0 + s1) + mA + em;
    alpha = act ? alpha_new : NEG_INF;

    if (act) hist[((size_t)t * BN + b) * 32 + j] = (unsigned char)barg;

    // compose chunk map: M_t[j] = M_{t-1}[barg]
    M = __builtin_amdgcn_ds_bpermute(bp_base + (barg << 2), M);
    if ((t & 31) == 0) {
      int c = (t >> 5) - 1;
      if (act) mmap[((size_t)c * BN + b) * 32 + j] = (unsigned char)M;
      M = j;
    }

    // gold-path numerator (loose tolerance; trans gathered from LDS)
    float trc = ltr[ptag * TN + jj];
    num_acc += (j == tg) ? (trc + em) : 0.0f;
    ptag = tg;
  }
  if (act) mmap[((size_t)15 * BN + b) * 32 + j] = (unsigned char)M;  // chunk 15 (t=481..511)

  // last tag: argmax_j (score + end), first-max-wins — bitwise match via exact compare + ctz
  float v = score + endv;                        // -inf on inactive lanes
  float mv = gmax32(v);
  unsigned long long bal = __ballot(v == mv);
  unsigned int gb = (unsigned int)(bal >> (tid & 32));
  int lt = __ffs(gb) - 1;
  num_acc += (j == lt) ? endv : 0.0f;
  float numerator = gsum32(num_acc);

  // logZ
  float va = alpha + endv;
  float m2 = gmax32(va);
  float se = __expf(va - m2);
  float ssum = gsum32(se);
  float logZ = __logf(ssum) + m2;

  if (j == 0) {
    atomicAdd(nll_out, (logZ - numerator) * (1.0f / BN));  // mean(logZ - num) == -mean(num - logZ)
    lastTagOut[b] = lt;
  }
}

// ============================ kernel 2: chunk-boundary states ============================
__global__ void crf_bstate(const unsigned char* __restrict__ mmap,
                           const int* __restrict__ lastTag,
                           int* __restrict__ estate) {
  int b = blockIdx.x * 256 + threadIdx.x;
  if (b >= BN) return;
  int s = lastTag[b];
  estate[15 * BN + b] = s;                 // state at t=511 (end of chunk 15)
#pragma unroll
  for (int c = 15; c >= 1; --c) {
    s = mmap[((size_t)c * BN + b) * 32 + s];   // state at t = 32*c
    estate[(c - 1) * BN + b] = s;              // = end state of chunk c-1
  }
}

// ============================ kernel 3: per-chunk parallel backtrack ============================
__global__ void crf_backtrack(const unsigned char* __restrict__ hist,
                              const int* __restrict__ estate,
                              float* __restrict__ path) {
  int b = blockIdx.x * 256 + threadIdx.x;  // coalesced over batch
  int c = blockIdx.y;
  int s = estate[c * BN + b];
  int te = (c == 15) ? (LN - 1) : 32 * (c + 1);
  for (int t = te; t > 32 * c; --t) {
    path[(size_t)t * BN + b] = (float)s;
    s = hist[((size_t)t * BN + b) * 32 + s];
  }
  if (c == 0) path[b] = (float)s;          // state at t=0
}

extern "C" void kernel_launch(void* const* d_in, const int* in_sizes, int n_in,
                              void* d_out, int out_size, void* d_ws, size_t ws_size,
                              hipStream_t stream) {
  const float* emis   = (const float*)d_in[0];
  const int*   tags   = (const int*)d_in[1];
  const float* trans  = (const float*)d_in[2];
  const float* startT = (const float*)d_in[3];
  const float* endT   = (const float*)d_in[4];
  float* out = (float*)d_out;

  unsigned char* hist = (unsigned char*)d_ws;                 // [512][4096][32] u8 = 64 MiB
  unsigned char* mmap = hist + (size_t)LN * BN * 32;          // [16][4096][32]  u8 =  2 MiB
  int* lastTag = (int*)(mmap + (size_t)16 * BN * 32);         // [4096] i32
  int* estate  = lastTag + BN;                                // [16][4096] i32

  hipMemsetAsync(d_out, 0, sizeof(float), stream);            // zero the NLL accumulator

  crf_main<<<dim3((BN * 32) / 256), 256, 0, stream>>>(emis, tags, trans, startT, endT,
                                                      out, hist, mmap, lastTag);
  crf_bstate<<<dim3(BN / 256), 256, 0, stream>>>(mmap, lastTag, estate);
  crf_backtrack<<<dim3(BN / 256, 16), 256, 0, stream>>>(hist, estate, out + 1);
}

// Round 2
// 678.179 us; speedup vs baseline: 1.2731x; 1.2731x over previous
//
#include <hip/hip_runtime.h>

#define TN 25
#define BN 4096
#define LN 512
#define NEG_INF (-__builtin_huge_valf())

// ---- 32-lane (half-wave) butterfly reductions via ds_swizzle (imm = xor<<10 | 0x1f) ----
__device__ __forceinline__ float gmax32(float x) {
  x = fmaxf(x, __int_as_float(__builtin_amdgcn_ds_swizzle(__float_as_int(x), 0x041F)));
  x = fmaxf(x, __int_as_float(__builtin_amdgcn_ds_swizzle(__float_as_int(x), 0x081F)));
  x = fmaxf(x, __int_as_float(__builtin_amdgcn_ds_swizzle(__float_as_int(x), 0x101F)));
  x = fmaxf(x, __int_as_float(__builtin_amdgcn_ds_swizzle(__float_as_int(x), 0x201F)));
  x = fmaxf(x, __int_as_float(__builtin_amdgcn_ds_swizzle(__float_as_int(x), 0x401F)));
  return x;
}
__device__ __forceinline__ float gsum32(float x) {
  x = x + __int_as_float(__builtin_amdgcn_ds_swizzle(__float_as_int(x), 0x041F));
  x = x + __int_as_float(__builtin_amdgcn_ds_swizzle(__float_as_int(x), 0x081F));
  x = x + __int_as_float(__builtin_amdgcn_ds_swizzle(__float_as_int(x), 0x101F));
  x = x + __int_as_float(__builtin_amdgcn_ds_swizzle(__float_as_int(x), 0x201F));
  x = x + __int_as_float(__builtin_amdgcn_ds_swizzle(__float_as_int(x), 0x401F));
  return x;
}

// Viterbi candidates: v[p] = (score[p] + trans[p][j]) + em  -- EXACT order match vs reference
template <int P>
__device__ __forceinline__ void vit_cand(int sci, const float (&tc)[TN], float em,
                                         float (&v)[TN]) {
  v[P] = (__int_as_float(__builtin_amdgcn_ds_swizzle(sci, (P << 5))) + tc[P]) + em;
  if constexpr (P + 1 < TN) vit_cand<P + 1>(sci, tc, em, v);
}

// Forward accumulation: s += exp(alpha[p]-mA) * exp(trans[p][j]), split into 2 accumulators
template <int P>
__device__ __forceinline__ void fwd_acc(int eai, const float (&ec)[TN], float& s0, float& s1) {
  float ep = __int_as_float(__builtin_amdgcn_ds_swizzle(eai, (P << 5)));
  if constexpr ((P & 1) == 0) { s0 = fmaf(ep, ec[P], s0); } else { s1 = fmaf(ep, ec[P], s1); }
  if constexpr (P + 1 < TN) fwd_acc<P + 1>(eai, ec, s0, s1);
}

// ==================== kernel 1: role-split — Viterbi waves + forward(NLL) waves ====================
// Block = 512 threads = 16 half-wave groups. Groups 0-7 (waves 0-3): Viterbi for batches
// base+0..7. Groups 8-15 (waves 4-7): forward algorithm + gold-path numerator for same batches.
// The two recursions are independent dependence chains -> co-resident waves double occupancy.
__global__ __launch_bounds__(512, 4) void crf_main(
    const float* __restrict__ emis, const int* __restrict__ tags,
    const float* __restrict__ trans, const float* __restrict__ startT,
    const float* __restrict__ endT, float* __restrict__ nll_out,
    unsigned char* __restrict__ hist, unsigned char* __restrict__ mmap,
    int* __restrict__ lastTagOut) {
  __shared__ float ltr[TN * TN];
  const int tid = threadIdx.x;
  for (int i = tid; i < TN * TN; i += 512) ltr[i] = trans[i];
  __syncthreads();

  const int j = tid & 31;
  const int grp = tid >> 5;                 // 0..15
  const int b = blockIdx.x * 8 + (grp & 7); // batch element
  const bool act = (j < TN);
  const int jj = act ? j : 0;
  const float endv = act ? endT[j] : NEG_INF;
  const float* emp = emis + (size_t)b * TN;
  const float em0 = act ? emp[j] : 0.0f;
  const float startv = act ? startT[j] : NEG_INF;

  if (grp < 8) {
    // ---------------- Viterbi role ----------------
    float tc[TN];
#pragma unroll
    for (int p = 0; p < TN; ++p) tc[p] = ltr[p * TN + jj];

    float score = startv + em0;             // exact: fl(start + em)
    int M = j;                              // chunk-composed backpointer map
    const int bp_base = (tid & 32) << 2;    // ds_bpermute byte base of this 32-group
    unsigned char* hp = hist + ((size_t)BN + b) * 32 + j;   // t=1 slot

#pragma unroll 1
    for (int t = 1; t < LN; ++t) {
      emp += (size_t)BN * TN;
      float em = act ? emp[j] : 0.0f;

      float v[TN];
      vit_cand<0>(__float_as_int(score), tc, em, v);

      // depth-5 tournament, left-biased (strict '>' for right) == jnp first-max-wins
      int ix[TN];
#pragma unroll
      for (int p = 0; p < TN; ++p) ix[p] = p;
#pragma unroll
      for (int s = 1; s < TN; s <<= 1) {
#pragma unroll
        for (int i = 0; i + s < TN; i += 2 * s) {
          bool g = v[i + s] > v[i];
          v[i] = g ? v[i + s] : v[i];
          ix[i] = g ? ix[i + s] : ix[i];
        }
      }
      score = v[0];
      int barg = ix[0];

      if (act) *hp = (unsigned char)barg;
      hp += (size_t)BN * 32;

      // compose chunk map: M_t[j] = M_{t-1}[barg]
      M = __builtin_amdgcn_ds_bpermute(bp_base + (barg << 2), M);
      if ((t & 31) == 0) {
        int c = (t >> 5) - 1;
        if (act) mmap[((size_t)c * BN + b) * 32 + j] = (unsigned char)M;
        M = j;
      }
    }
    if (act) mmap[((size_t)15 * BN + b) * 32 + j] = (unsigned char)M;

    // last tag: argmax_j (score + end), first-max-wins bitwise
    float vv = score + endv;
    float mv = gmax32(vv);
    unsigned long long bal = __ballot(vv == mv);
    unsigned int gb = (unsigned int)(bal >> (tid & 32));
    int lt = __ffs(gb) - 1;
    if (j == 0) lastTagOut[b] = lt;
  } else {
    // ---------------- forward (log-partition) + gold-path numerator role ----------------
    float ec[TN];
#pragma unroll
    for (int p = 0; p < TN; ++p) ec[p] = __expf(ltr[p * TN + jj]);

    int tag = tags[b];
    float alpha = startv + em0;             // -inf on inactive lanes
    float num_acc = (j == tag) ? alpha : 0.0f;
    int ptag = tag;

#pragma unroll 1
    for (int t = 1; t < LN; ++t) {
      emp += (size_t)BN * TN;
      float em = act ? emp[j] : 0.0f;
      int tg = tags[(size_t)t * BN + b];

      // normalizer: lane-0 alpha broadcast (spread across states <= ~12, exp stays in range;
      // NLL tolerance is huge). Replaces 5-deep gmax chain with 1 swizzle.
      float mA = __int_as_float(__builtin_amdgcn_ds_swizzle(__float_as_int(alpha), 0x0000));
      float ea = __expf(alpha - mA);        // 0 on inactive lanes

      float s0 = 0.0f, s1 = 0.0f;
      fwd_acc<0>(__float_as_int(ea), ec, s0, s1);
      alpha = act ? (__logf(s0 + s1) + mA + em) : NEG_INF;

      float trc = ltr[ptag * TN + jj];
      num_acc += (j == tg) ? (trc + em) : 0.0f;
      ptag = tg;
    }

    num_acc += (j == ptag) ? endv : 0.0f;   // end_transitions[gold last tag]
    float numerator = gsum32(num_acc);

    float va = alpha + endv;
    float m2 = gmax32(va);
    float ssum = gsum32(__expf(va - m2));
    float logZ = __logf(ssum) + m2;

    if (j == 0) atomicAdd(nll_out, (logZ - numerator) * (1.0f / BN));
  }
}

// ============================ kernel 2: chunk-boundary states ============================
__global__ void crf_bstate(const unsigned char* __restrict__ mmap,
                           const int* __restrict__ lastTag,
                           int* __restrict__ estate) {
  int b = blockIdx.x * 256 + threadIdx.x;
  if (b >= BN) return;
  int s = lastTag[b];
  estate[15 * BN + b] = s;
#pragma unroll
  for (int c = 15; c >= 1; --c) {
    s = mmap[((size_t)c * BN + b) * 32 + s];
    estate[(c - 1) * BN + b] = s;
  }
}

// ============================ kernel 3: per-chunk parallel backtrack ============================
__global__ void crf_backtrack(const unsigned char* __restrict__ hist,
                              const int* __restrict__ estate,
                              float* __restrict__ path) {
  int b = blockIdx.x * 256 + threadIdx.x;
  int c = blockIdx.y;
  int s = estate[c * BN + b];
  int te = (c == 15) ? (LN - 1) : 32 * (c + 1);
  for (int t = te; t > 32 * c; --t) {
    path[(size_t)t * BN + b] = (float)s;
    s = hist[((size_t)t * BN + b) * 32 + s];
  }
  if (c == 0) path[b] = (float)s;
}

extern "C" void kernel_launch(void* const* d_in, const int* in_sizes, int n_in,
                              void* d_out, int out_size, void* d_ws, size_t ws_size,
                              hipStream_t stream) {
  const float* emis   = (const float*)d_in[0];
  const int*   tags   = (const int*)d_in[1];
  const float* trans  = (const float*)d_in[2];
  const float* startT = (const float*)d_in[3];
  const float* endT   = (const float*)d_in[4];
  float* out = (float*)d_out;

  unsigned char* hist = (unsigned char*)d_ws;                 // [512][4096][32] u8 = 64 MiB
  unsigned char* mmap = hist + (size_t)LN * BN * 32;          // [16][4096][32]  u8 =  2 MiB
  int* lastTag = (int*)(mmap + (size_t)16 * BN * 32);         // [4096] i32
  int* estate  = lastTag + BN;                                // [16][4096] i32

  hipMemsetAsync(d_out, 0, sizeof(float), stream);            // zero the NLL accumulator

  crf_main<<<dim3(BN / 8), 512, 0, stream>>>(emis, tags, trans, startT, endT,
                                             out, hist, mmap, lastTag);
  crf_bstate<<<dim3(BN / 256), 256, 0, stream>>>(mmap, lastTag, estate);
  crf_backtrack<<<dim3(BN / 256, 16), 256, 0, stream>>>(hist, estate, out + 1);
}

// Round 4
// 651.739 us; speedup vs baseline: 1.3247x; 1.0406x over previous
//
#include <hip/hip_runtime.h>

#define TN 25
#define BN 4096
#define LN 512
#define NEG_INF (-__builtin_huge_valf())

// ---- 32-lane (half-wave) butterfly reductions via ds_swizzle (imm = xor<<10 | 0x1f) ----
__device__ __forceinline__ float gmax32(float x) {
  x = fmaxf(x, __int_as_float(__builtin_amdgcn_ds_swizzle(__float_as_int(x), 0x041F)));
  x = fmaxf(x, __int_as_float(__builtin_amdgcn_ds_swizzle(__float_as_int(x), 0x081F)));
  x = fmaxf(x, __int_as_float(__builtin_amdgcn_ds_swizzle(__float_as_int(x), 0x101F)));
  x = fmaxf(x, __int_as_float(__builtin_amdgcn_ds_swizzle(__float_as_int(x), 0x201F)));
  x = fmaxf(x, __int_as_float(__builtin_amdgcn_ds_swizzle(__float_as_int(x), 0x401F)));
  return x;
}
__device__ __forceinline__ float gsum32(float x) {
  x = x + __int_as_float(__builtin_amdgcn_ds_swizzle(__float_as_int(x), 0x041F));
  x = x + __int_as_float(__builtin_amdgcn_ds_swizzle(__float_as_int(x), 0x081F));
  x = x + __int_as_float(__builtin_amdgcn_ds_swizzle(__float_as_int(x), 0x101F));
  x = x + __int_as_float(__builtin_amdgcn_ds_swizzle(__float_as_int(x), 0x201F));
  x = x + __int_as_float(__builtin_amdgcn_ds_swizzle(__float_as_int(x), 0x401F));
  return x;
}

// read the 25-float group vector from LDS via 6x b128 + 1x b32 (uniform addr = broadcast)
__device__ __forceinline__ void read_vec25(const float* __restrict__ svec, float (&sp)[TN]) {
  const float4 q0 = *(const float4*)(svec + 0);
  const float4 q1 = *(const float4*)(svec + 4);
  const float4 q2 = *(const float4*)(svec + 8);
  const float4 q3 = *(const float4*)(svec + 12);
  const float4 q4 = *(const float4*)(svec + 16);
  const float4 q5 = *(const float4*)(svec + 20);
  sp[0]=q0.x;  sp[1]=q0.y;  sp[2]=q0.z;  sp[3]=q0.w;
  sp[4]=q1.x;  sp[5]=q1.y;  sp[6]=q1.z;  sp[7]=q1.w;
  sp[8]=q2.x;  sp[9]=q2.y;  sp[10]=q2.z; sp[11]=q2.w;
  sp[12]=q3.x; sp[13]=q3.y; sp[14]=q3.z; sp[15]=q3.w;
  sp[16]=q4.x; sp[17]=q4.y; sp[18]=q4.z; sp[19]=q4.w;
  sp[20]=q5.x; sp[21]=q5.y; sp[22]=q5.z; sp[23]=q5.w;
  sp[24]=svec[24];
}

// ==================== kernel 1: role-split — Viterbi waves + forward(NLL) waves ====================
// Block = 512 threads = 16 half-wave groups. Groups 0-7: Viterbi for batches base+0..7.
// Groups 8-15: forward algorithm + gold-path numerator for the same batches.
// Per-group score/ea vectors are exchanged through a private LDS row (write 1 + read 7 DS ops,
// all uniform-address broadcasts) instead of 25 ds_swizzles; trans columns are PINNED in VGPRs.
__global__ __launch_bounds__(512, 4) void crf_main(
    const float* __restrict__ emis, const int* __restrict__ tags,
    const float* __restrict__ trans, const float* __restrict__ startT,
    const float* __restrict__ endT, float* __restrict__ nll_out,
    unsigned char* __restrict__ hist, unsigned char* __restrict__ mmap,
    int* __restrict__ lastTagOut) {
  __shared__ float ltr[TN * TN];
  __shared__ float sbuf[16][28];            // 28-float stride: halves of a wave hit disjoint banks
  const int tid = threadIdx.x;
  for (int i = tid; i < TN * TN; i += 512) ltr[i] = trans[i];
  __syncthreads();

  const int j = tid & 31;
  const int grp = tid >> 5;                 // 0..15
  const int b = blockIdx.x * 8 + (grp & 7); // batch element
  const bool act = (j < TN);
  const int jj = act ? j : 0;
  const float endv = act ? endT[j] : NEG_INF;
  const float* emp = emis + (size_t)b * TN;
  const float em0 = act ? emp[j] : 0.0f;
  const float startv = act ? startT[j] : NEG_INF;
  float* svec = sbuf[grp];

  if (grp < 8) {
    // ---------------- Viterbi role ----------------
    float tc[TN];
#pragma unroll
    for (int p = 0; p < TN; ++p) {
      tc[p] = ltr[p * TN + jj];
      asm volatile("" : "+v"(tc[p]));       // pin in VGPR: forbid rematerialization from LDS
    }

    float score = startv + em0;             // exact: fl(start + em)
    if (act) svec[j] = score;
    int M = j;                              // chunk-composed backpointer map
    const int bp_base = (tid & 32) << 2;    // ds_bpermute byte base of this 32-group
    unsigned char* hp = hist + ((size_t)BN + b) * 32 + j;   // t=1 slot

#pragma unroll 1
    for (int t = 1; t < LN; ++t) {
      emp += (size_t)BN * TN;
      float em = act ? emp[j] : 0.0f;

      float sp[TN];
      read_vec25(svec, sp);                 // previous scores (in-order DS within wave)

      float v[TN]; int ix[TN];
#pragma unroll
      for (int p = 0; p < TN; ++p) {        // EXACT ref order: (score + trans) + em
        v[p] = (sp[p] + tc[p]) + em;
        ix[p] = p;
      }
      // depth-5 tournament, left-biased (strict '>' for right) == jnp first-max-wins
#pragma unroll
      for (int s = 1; s < TN; s <<= 1) {
#pragma unroll
        for (int i2 = 0; i2 + s < TN; i2 += 2 * s) {
          bool g = v[i2 + s] > v[i2];
          v[i2] = g ? v[i2 + s] : v[i2];
          ix[i2] = g ? ix[i2 + s] : ix[i2];
        }
      }
      score = v[0];
      int barg = ix[0];

      if (act) svec[j] = score;             // publish for next step (same wave -> in-order)
      if (act) *hp = (unsigned char)barg;
      hp += (size_t)BN * 32;

      // compose chunk map: M_t[j] = M_{t-1}[barg]
      M = __builtin_amdgcn_ds_bpermute(bp_base + (barg << 2), M);
      if ((t & 31) == 0) {
        int c = (t >> 5) - 1;
        if (act) mmap[((size_t)c * BN + b) * 32 + j] = (unsigned char)M;
        M = j;
      }
    }
    if (act) mmap[((size_t)15 * BN + b) * 32 + j] = (unsigned char)M;

    // last tag: argmax_j (score + end), first-max-wins bitwise
    float vv = score + endv;
    float mv = gmax32(vv);
    unsigned long long bal = __ballot(vv == mv);
    unsigned int gb = (unsigned int)(bal >> (tid & 32));
    int lt = __ffs(gb) - 1;
    if (j == 0) lastTagOut[b] = lt;
  } else {
    // ---------------- forward (log-partition) + gold-path numerator role ----------------
    float ec[TN];
#pragma unroll
    for (int p = 0; p < TN; ++p) {
      ec[p] = __expf(ltr[p * TN + jj]);
      asm volatile("" : "+v"(ec[p]));       // pin in VGPR
    }

    int tag = tags[b];
    float alpha = startv + em0;             // -inf on inactive lanes
    float num_acc = (j == tag) ? alpha : 0.0f;
    int ptag = tag;

#pragma unroll 1
    for (int t = 1; t < LN; ++t) {
      emp += (size_t)BN * TN;
      float em = act ? emp[j] : 0.0f;
      int tg = tags[(size_t)t * BN + b];

      // normalizer: lane-0 alpha broadcast (spread across states is small; NLL slack is huge)
      float mA = __int_as_float(__builtin_amdgcn_ds_swizzle(__float_as_int(alpha), 0x0000));
      float ea = __expf(alpha - mA);        // 0 on inactive lanes
      if (act) svec[j] = ea;                // publish (same wave -> in-order, no barrier)

      float ep[TN];
      read_vec25(svec, ep);

      float s0 = 0.0f, s1 = 0.0f;
#pragma unroll
      for (int p = 0; p < TN; p += 2) s0 = fmaf(ep[p], ec[p], s0);
#pragma unroll
      for (int p = 1; p < TN; p += 2) s1 = fmaf(ep[p], ec[p], s1);
      alpha = act ? (__logf(s0 + s1) + mA + em) : NEG_INF;

      float trc = ltr[ptag * TN + jj];
      num_acc += (j == tg) ? (trc + em) : 0.0f;
      ptag = tg;
    }

    num_acc += (j == ptag) ? endv : 0.0f;   // end_transitions[gold last tag]
    float numerator = gsum32(num_acc);

    float va = alpha + endv;
    float m2 = gmax32(va);
    float ssum = gsum32(__expf(va - m2));
    float logZ = __logf(ssum) + m2;

    if (j == 0) atomicAdd(nll_out, (logZ - numerator) * (1.0f / BN));
  }
}

// ============================ kernel 2: chunk-boundary states ============================
__global__ void crf_bstate(const unsigned char* __restrict__ mmap,
                           const int* __restrict__ lastTag,
                           int* __restrict__ estate) {
  int b = blockIdx.x * 256 + threadIdx.x;
  if (b >= BN) return;
  int s = lastTag[b];
  estate[15 * BN + b] = s;
#pragma unroll
  for (int c = 15; c >= 1; --c) {
    s = mmap[((size_t)c * BN + b) * 32 + s];
    estate[(c - 1) * BN + b] = s;
  }
}

// ============================ kernel 3: per-chunk parallel backtrack ============================
__global__ void crf_backtrack(const unsigned char* __restrict__ hist,
                              const int* __restrict__ estate,
                              float* __restrict__ path) {
  int b = blockIdx.x * 256 + threadIdx.x;
  int c = blockIdx.y;
  int s = estate[c * BN + b];
  int te = (c == 15) ? (LN - 1) : 32 * (c + 1);
  for (int t = te; t > 32 * c; --t) {
    path[(size_t)t * BN + b] = (float)s;
    s = hist[((size_t)t * BN + b) * 32 + s];
  }
  if (c == 0) path[b] = (float)s;
}

extern "C" void kernel_launch(void* const* d_in, const int* in_sizes, int n_in,
                              void* d_out, int out_size, void* d_ws, size_t ws_size,
                              hipStream_t stream) {
  const float* emis   = (const float*)d_in[0];
  const int*   tags   = (const int*)d_in[1];
  const float* trans  = (const float*)d_in[2];
  const float* startT = (const float*)d_in[3];
  const float* endT   = (const float*)d_in[4];
  float* out = (float*)d_out;

  unsigned char* hist = (unsigned char*)d_ws;                 // [512][4096][32] u8 = 64 MiB
  unsigned char* mmap = hist + (size_t)LN * BN * 32;          // [16][4096][32]  u8 =  2 MiB
  int* lastTag = (int*)(mmap + (size_t)16 * BN * 32);         // [4096] i32
  int* estate  = lastTag + BN;                                // [16][4096] i32

  hipMemsetAsync(d_out, 0, sizeof(float), stream);            // zero the NLL accumulator

  crf_main<<<dim3(BN / 8), 512, 0, stream>>>(emis, tags, trans, startT, endT,
                                             out, hist, mmap, lastTag);
  crf_bstate<<<dim3(BN / 256), 256, 0, stream>>>(mmap, lastTag, estate);
  crf_backtrack<<<dim3(BN / 256, 16), 256, 0, stream>>>(hist, estate, out + 1);
}